// Round 3
// baseline (121.878 us; speedup 1.0000x reference)
//
#include <hip/hip_runtime.h>
#include <math.h>

// Problem constants
#define B_     16
#define O_     16
#define NPERM  240          // O*(O-1)
#define NUM_IN 160          // 32 + 2*32 + 2*32
#define NI4    40           // NUM_IN/4
#define RC     96           // R*C
#define BPB    8            // (b,perm) pairs per block in main kernel
#define MAIN_GRID ((B_ * NPERM) / BPB)   // 480

// d_out float offsets
#define OFF_NULLARY 0            // 16
#define OFF_UNARY   16           // 256
#define OFF_BINARY  272          // 3840
#define OFF_AK      4112         // 46080
#define OFF_OK      50192        // 96

// ws float offsets
#define WS_WT   0                // transposed [rc][NUM_IN] = 15360
#define WS_VT   15360            // 15360
#define WS_OK   30720            // 96
#define WS_R01  30816            // rules r=0 [3840] then r=1 [3840]
#define WS_CNT  38496            // 1 int ticket counter

// ---------------- Kernel 1: softmax(and_kernel) -> ak + transposed w/v tables;
// sigmoid(or) -> ok; zero the ticket counter (ws is re-poisoned 0xAA per call)
__global__ __launch_bounds__(256) void prep_kernel(
    const float* __restrict__ and_k,   // (R,C,NUM_IN,3) flat
    const float* __restrict__ or_k,    // (R,C) flat
    const float* __restrict__ temp,    // (1,)
    float* __restrict__ ak_out,        // d_out + OFF_AK
    float* __restrict__ ok_out,        // d_out + OFF_OK
    float* __restrict__ wt,            // ws: [rc][i]
    float* __restrict__ vt,            // ws: [rc][i]
    float* __restrict__ okw,           // ws: [rc]
    int*   __restrict__ counter)       // ws ticket
{
    int gid = blockIdx.x * 256 + threadIdx.x;   // 0 .. 15359
    float tinv = 1.0f / temp[0];
    if (gid == 0) *counter = 0;
    if (gid < RC * NUM_IN) {
        float a0 = and_k[gid * 3 + 0] * tinv;
        float a1 = and_k[gid * 3 + 1] * tinv;
        float a2 = and_k[gid * 3 + 2] * tinv;
        float m  = fmaxf(a0, fmaxf(a1, a2));
        float e0 = __expf(a0 - m), e1 = __expf(a1 - m), e2 = __expf(a2 - m);
        float s  = 1.0f / (e0 + e1 + e2);
        float k0 = e0 * s, k1 = e1 * s, k2 = e2 * s;
        ak_out[gid * 3 + 0] = k0;
        ak_out[gid * 3 + 1] = k1;
        ak_out[gid * 3 + 2] = k2;
        wt[gid] = k0 - k1;        // conj_eval = x*w + v
        vt[gid] = k1 + k2;
    }
    if (gid < RC) {
        float o = 1.0f / (1.0f + __expf(-or_k[gid] * tinv));
        ok_out[gid] = o;
        okw[gid]    = o;
    }
}

// ---------------- Kernel 2: main conjunct/disjunct computation + fused finish
// One block per BPB (b,perm) pairs. Lanes 0..95 own one rc each; table read
// as float4 along i (L2-resident); x broadcast from LDS. Last block to finish
// (device-scope ticket) performs the nullary/unary probsum reductions.
__global__ __launch_bounds__(128) void main_kernel(
    const float* __restrict__ nullary,  // (B,32)
    const float* __restrict__ unary,    // (B,16,32)
    const float* __restrict__ binary,   // (B,16,15,32)
    const float* __restrict__ wt,       // ws: [rc][i]
    const float* __restrict__ vt,       // ws: [rc][i]
    const float* __restrict__ okw,      // ws: [rc]
    float* __restrict__ binary_out,     // d_out + OFF_BINARY, [3840]
    float* __restrict__ rules01,        // ws: r0[3840], r1[3840]
    int*   __restrict__ counter,        // ws ticket
    float* __restrict__ nullary_out,    // d_out + OFF_NULLARY, [16]
    float* __restrict__ unary_out)      // d_out + OFF_UNARY, [256]
{
    int bp0 = blockIdx.x * BPB;
    __shared__ float xs[BPB * NUM_IN];
    __shared__ int   ticket;
    __shared__ float wp[2];

    int t = threadIdx.x;
    // Gather phase: BPB*160 floats, 128 threads, 32-float coalesced runs
    for (int idx = t; idx < BPB * NUM_IN; idx += 128) {
        int bpl = idx / NUM_IN;
        int i   = idx - bpl * NUM_IN;
        int bp  = bp0 + bpl;
        int bt  = bp / NPERM;
        int p   = bp - bt * NPERM;
        int a   = p / 15;
        int rem = p - a * 15;
        int b   = rem + (rem >= a);
        int bprime = rem;                 // b - (b > a)
        int aprime = a - (a > b);
        int seg = i >> 5, j = i & 31;
        float v;
        if      (seg == 0) v = nullary[bt * 32 + j];
        else if (seg == 1) v = unary[(bt * 16 + a) * 32 + j];
        else if (seg == 2) v = unary[(bt * 16 + b) * 32 + j];
        else if (seg == 3) v = binary[((bt * 16 + a) * 15 + bprime) * 32 + j];
        else               v = binary[((bt * 16 + b) * 15 + aprime) * 32 + j];
        xs[idx] = v;
    }
    __syncthreads();

    if (t < RC) {
        const float4* w4 = (const float4*)wt + t * NI4;
        const float4* v4 = (const float4*)vt + t * NI4;
        const float4* x4 = (const float4*)xs;           // [BPB][NI4]
        float cA[BPB], cB[BPB];
        #pragma unroll
        for (int l = 0; l < BPB; ++l) { cA[l] = 1.0f; cB[l] = 1.0f; }

        #pragma unroll 2
        for (int s = 0; s < NI4; ++s) {
            float4 w = w4[s];
            float4 v = v4[s];
            #pragma unroll
            for (int l = 0; l < BPB; ++l) {
                float4 x = x4[l * NI4 + s];             // LDS broadcast b128
                cA[l] *= fmaf(x.x, w.x, v.x);
                cB[l] *= fmaf(x.y, w.y, v.y);
                cA[l] *= fmaf(x.z, w.z, v.z);
                cB[l] *= fmaf(x.w, w.w, v.w);
            }
        }

        float o = okw[t];
        int r = t >> 5;
        #pragma unroll
        for (int l = 0; l < BPB; ++l) {
            float d = 1.0f - (cA[l] * cB[l]) * o;
            // product across the 32 c-lanes of this r-group
            #pragma unroll
            for (int off = 1; off < 32; off <<= 1)
                d *= __shfl_xor(d, off, 32);
            if ((t & 31) == 0) {
                float dis = 1.0f - d;
                int bp = bp0 + l;
                if (r == 2) binary_out[bp] = dis;
                else        rules01[r * (B_ * NPERM) + bp] = dis;
            }
        }
    }

    // ---- fused finish: last block to complete does the reductions ----
    __threadfence();                        // release our rules01 writes
    if (t == 0) ticket = atomicAdd(counter, 1);
    __syncthreads();
    if (ticket != MAIN_GRID - 1) return;
    __threadfence();                        // acquire all blocks' writes

    const float* r0 = rules01;
    const float* r1 = rules01 + B_ * NPERM;
    for (int bt = 0; bt < B_; ++bt) {
        // unary: 16 o1-groups x 16 lanes = 256 slots, 128 threads -> 2 passes
        #pragma unroll
        for (int pass = 0; pass < 2; ++pass) {
            int o1 = (t >> 4) + pass * 8;
            int l  = t & 15;
            float v = (l < 15) ? (1.0f - r1[bt * NPERM + o1 * 15 + l]) : 1.0f;
            #pragma unroll
            for (int off = 1; off < 16; off <<= 1)
                v *= __shfl_xor(v, off, 16);
            if (l == 0) unary_out[bt * 16 + o1] = 1.0f - v;
        }
        // nullary: product over all 240 perms (each thread folds 2)
        float a = 1.0f - r0[bt * NPERM + t];                       // t < 128 < 240
        float b = (t + 128 < NPERM) ? (1.0f - r0[bt * NPERM + t + 128]) : 1.0f;
        float v = a * b;
        #pragma unroll
        for (int off = 1; off < 64; off <<= 1)
            v *= __shfl_xor(v, off, 64);
        if ((t & 63) == 0) wp[t >> 6] = v;
        __syncthreads();
        if (t == 0) nullary_out[bt] = 1.0f - wp[0] * wp[1];
        __syncthreads();
    }
}

extern "C" void kernel_launch(void* const* d_in, const int* in_sizes, int n_in,
                              void* d_out, int out_size, void* d_ws, size_t ws_size,
                              hipStream_t stream) {
    const float* nullary = (const float*)d_in[0];   // (16,32)
    const float* unary   = (const float*)d_in[1];   // (16,16,32)
    const float* binary  = (const float*)d_in[2];   // (16,16,15,32)
    const float* and_k   = (const float*)d_in[3];   // (3,32,160,3)
    const float* or_k    = (const float*)d_in[4];   // (3,32)
    const float* temp    = (const float*)d_in[5];   // (1,)

    float* out = (float*)d_out;
    float* ws  = (float*)d_ws;

    float* wt      = ws + WS_WT;
    float* vt      = ws + WS_VT;
    float* okw     = ws + WS_OK;
    float* rules01 = ws + WS_R01;
    int*   counter = (int*)(ws + WS_CNT);

    prep_kernel<<<60, 256, 0, stream>>>(and_k, or_k, temp,
                                        out + OFF_AK, out + OFF_OK,
                                        wt, vt, okw, counter);
    main_kernel<<<MAIN_GRID, 128, 0, stream>>>(nullary, unary, binary,
                                               wt, vt, okw,
                                               out + OFF_BINARY, rules01, counter,
                                               out + OFF_NULLARY, out + OFF_UNARY);
}

// Round 4
// 88.591 us; speedup vs baseline: 1.3757x; 1.3757x over previous
//
#include <hip/hip_runtime.h>
#include <math.h>

// Problem constants
#define B_     16
#define O_     16
#define NPERM  240          // O*(O-1)
#define NUM_IN 160          // 32 + 2*32 + 2*32
#define NI4    40           // NUM_IN/4
#define RC     96           // R*C
#define BPB    8            // (b,perm) pairs per block in main kernel
#define MAIN_GRID ((B_ * NPERM) / BPB)   // 240

// d_out float offsets
#define OFF_NULLARY 0            // 16
#define OFF_UNARY   16           // 256
#define OFF_BINARY  272          // 3840
#define OFF_AK      4112         // 46080
#define OFF_OK      50192        // 96

// ws float offsets
#define WS_WT   0                // transposed [rc][NUM_IN] = 15360
#define WS_VT   15360            // 15360
#define WS_OK   30720            // 96
#define WS_R01  30816            // rules r=0 [3840] then r=1 [3840]

// ---------------- Kernel 1: softmax(and_kernel) -> ak + transposed w/v tables;
// sigmoid(or) -> ok.  gid = rc*NUM_IN + i matches both the and_kernel layout
// and the [rc][i] table layout -> fully coalesced.
__global__ __launch_bounds__(256) void prep_kernel(
    const float* __restrict__ and_k,   // (R,C,NUM_IN,3) flat
    const float* __restrict__ or_k,    // (R,C) flat
    const float* __restrict__ temp,    // (1,)
    float* __restrict__ ak_out,        // d_out + OFF_AK
    float* __restrict__ ok_out,        // d_out + OFF_OK
    float* __restrict__ wt,            // ws: [rc][i]
    float* __restrict__ vt,            // ws: [rc][i]
    float* __restrict__ okw)           // ws: [rc]
{
    int gid = blockIdx.x * 256 + threadIdx.x;   // 0 .. 15359
    float tinv = 1.0f / temp[0];
    if (gid < RC * NUM_IN) {
        float a0 = and_k[gid * 3 + 0] * tinv;
        float a1 = and_k[gid * 3 + 1] * tinv;
        float a2 = and_k[gid * 3 + 2] * tinv;
        float m  = fmaxf(a0, fmaxf(a1, a2));
        float e0 = __expf(a0 - m), e1 = __expf(a1 - m), e2 = __expf(a2 - m);
        float s  = 1.0f / (e0 + e1 + e2);
        float k0 = e0 * s, k1 = e1 * s, k2 = e2 * s;
        ak_out[gid * 3 + 0] = k0;
        ak_out[gid * 3 + 1] = k1;
        ak_out[gid * 3 + 2] = k2;
        wt[gid] = k0 - k1;        // conj_eval = x*w + v
        vt[gid] = k1 + k2;
    }
    if (gid < RC) {
        float o = 1.0f / (1.0f + __expf(-or_k[gid] * tinv));
        ok_out[gid] = o;
        okw[gid]    = o;
    }
}

// ---------------- Kernel 2: main conjunct/disjunct computation
// One block per BPB (b,perm) pairs. Lanes 0..95 own one rc each; table read
// as float4 along i (L2-resident); x broadcast from LDS. NO fences/atomics:
// a device-scope fence per block cost ~60us across the grid in R3.
__global__ __launch_bounds__(128) void main_kernel(
    const float* __restrict__ nullary,  // (B,32)
    const float* __restrict__ unary,    // (B,16,32)
    const float* __restrict__ binary,   // (B,16,15,32)
    const float* __restrict__ wt,       // ws: [rc][i]
    const float* __restrict__ vt,       // ws: [rc][i]
    const float* __restrict__ okw,      // ws: [rc]
    float* __restrict__ binary_out,     // d_out + OFF_BINARY, [3840]
    float* __restrict__ rules01)        // ws: r0[3840], r1[3840]
{
    int bp0 = blockIdx.x * BPB;
    __shared__ float xs[BPB * NUM_IN];

    int t = threadIdx.x;
    // Gather phase: BPB*160 floats, 128 threads, 32-float coalesced runs
    for (int idx = t; idx < BPB * NUM_IN; idx += 128) {
        int bpl = idx / NUM_IN;
        int i   = idx - bpl * NUM_IN;
        int bp  = bp0 + bpl;
        int bt  = bp / NPERM;
        int p   = bp - bt * NPERM;
        int a   = p / 15;
        int rem = p - a * 15;
        int b   = rem + (rem >= a);
        int bprime = rem;                 // b - (b > a)
        int aprime = a - (a > b);
        int seg = i >> 5, j = i & 31;
        float v;
        if      (seg == 0) v = nullary[bt * 32 + j];
        else if (seg == 1) v = unary[(bt * 16 + a) * 32 + j];
        else if (seg == 2) v = unary[(bt * 16 + b) * 32 + j];
        else if (seg == 3) v = binary[((bt * 16 + a) * 15 + bprime) * 32 + j];
        else               v = binary[((bt * 16 + b) * 15 + aprime) * 32 + j];
        xs[idx] = v;
    }
    __syncthreads();

    if (t < RC) {
        const float4* w4 = (const float4*)wt + t * NI4;
        const float4* v4 = (const float4*)vt + t * NI4;
        const float4* x4 = (const float4*)xs;           // [BPB][NI4]
        float cA[BPB], cB[BPB];
        #pragma unroll
        for (int l = 0; l < BPB; ++l) { cA[l] = 1.0f; cB[l] = 1.0f; }

        #pragma unroll 2
        for (int s = 0; s < NI4; ++s) {
            float4 w = w4[s];
            float4 v = v4[s];
            #pragma unroll
            for (int l = 0; l < BPB; ++l) {
                float4 x = x4[l * NI4 + s];             // LDS broadcast b128
                cA[l] *= fmaf(x.x, w.x, v.x);
                cB[l] *= fmaf(x.y, w.y, v.y);
                cA[l] *= fmaf(x.z, w.z, v.z);
                cB[l] *= fmaf(x.w, w.w, v.w);
            }
        }

        float o = okw[t];
        int r = t >> 5;
        #pragma unroll
        for (int l = 0; l < BPB; ++l) {
            float d = 1.0f - (cA[l] * cB[l]) * o;
            // product across the 32 c-lanes of this r-group
            #pragma unroll
            for (int off = 1; off < 32; off <<= 1)
                d *= __shfl_xor(d, off, 32);
            if ((t & 31) == 0) {
                float dis = 1.0f - d;
                int bp = bp0 + l;
                if (r == 2) binary_out[bp] = dis;
                else        rules01[r * (B_ * NPERM) + bp] = dis;
            }
        }
    }
}

// ---------------- Kernel 3: probsum reductions for nullary (240->1) and unary (15->1)
__global__ __launch_bounds__(256) void finish_kernel(
    const float* __restrict__ rules01,   // ws
    float* __restrict__ nullary_out,     // d_out + OFF_NULLARY, [16]
    float* __restrict__ unary_out)       // d_out + OFF_UNARY, [256]
{
    int bt = blockIdx.x;    // 0..15
    int t  = threadIdx.x;
    const float* r0 = rules01;
    const float* r1 = rules01 + B_ * NPERM;

    // unary: o1 = t/16, lane-in-group covers the 15 o2 slots
    {
        int o1 = t >> 4, l = t & 15;
        float v = (l < 15) ? (1.0f - r1[bt * NPERM + o1 * 15 + l]) : 1.0f;
        #pragma unroll
        for (int off = 1; off < 16; off <<= 1)
            v *= __shfl_xor(v, off, 16);
        if (l == 0) unary_out[bt * 16 + o1] = 1.0f - v;
    }

    // nullary: product over all 240 perms
    {
        float v = (t < NPERM) ? (1.0f - r0[bt * NPERM + t]) : 1.0f;
        #pragma unroll
        for (int off = 1; off < 64; off <<= 1)
            v *= __shfl_xor(v, off, 64);
        __shared__ float wprod[4];
        if ((t & 63) == 0) wprod[t >> 6] = v;
        __syncthreads();
        if (t == 0)
            nullary_out[bt] = 1.0f - wprod[0] * wprod[1] * wprod[2] * wprod[3];
    }
}

extern "C" void kernel_launch(void* const* d_in, const int* in_sizes, int n_in,
                              void* d_out, int out_size, void* d_ws, size_t ws_size,
                              hipStream_t stream) {
    const float* nullary = (const float*)d_in[0];   // (16,32)
    const float* unary   = (const float*)d_in[1];   // (16,16,32)
    const float* binary  = (const float*)d_in[2];   // (16,16,15,32)
    const float* and_k   = (const float*)d_in[3];   // (3,32,160,3)
    const float* or_k    = (const float*)d_in[4];   // (3,32)
    const float* temp    = (const float*)d_in[5];   // (1,)

    float* out = (float*)d_out;
    float* ws  = (float*)d_ws;

    float* wt      = ws + WS_WT;
    float* vt      = ws + WS_VT;
    float* okw     = ws + WS_OK;
    float* rules01 = ws + WS_R01;

    prep_kernel<<<60, 256, 0, stream>>>(and_k, or_k, temp,
                                        out + OFF_AK, out + OFF_OK,
                                        wt, vt, okw);
    main_kernel<<<MAIN_GRID, 128, 0, stream>>>(nullary, unary, binary,
                                               wt, vt, okw,
                                               out + OFF_BINARY, rules01);
    finish_kernel<<<B_, 256, 0, stream>>>(rules01,
                                          out + OFF_NULLARY, out + OFF_UNARY);
}

// Round 5
// 84.979 us; speedup vs baseline: 1.4342x; 1.0425x over previous
//
#include <hip/hip_runtime.h>
#include <math.h>

// Problem constants
#define B_     16
#define O_     16
#define NPERM  240          // O*(O-1)
#define NUM_IN 160          // 32 + 2*32 + 2*32
#define NI4    40           // NUM_IN/4
#define RC     96           // R*C
#define BPB    4            // (b,perm) pairs per block — measured best (R2: 85.4us vs BPB=8: 88.6us)
#define MAIN_GRID ((B_ * NPERM) / BPB)   // 960

// d_out float offsets
#define OFF_NULLARY 0            // 16
#define OFF_UNARY   16           // 256
#define OFF_BINARY  272          // 3840
#define OFF_AK      4112         // 46080
#define OFF_OK      50192        // 96

// ws float offsets
#define WS_WT   0                // transposed [rc][NUM_IN] = 15360
#define WS_VT   15360            // 15360
#define WS_OK   30720            // 96
#define WS_R01  30816            // rules r=0 [3840] then r=1 [3840]

// ---------------- Kernel 1: softmax(and_kernel) -> ak + transposed w/v tables;
// sigmoid(or) -> ok.  gid = rc*NUM_IN + i matches both the and_kernel layout
// and the [rc][i] table layout -> fully coalesced.
__global__ __launch_bounds__(256) void prep_kernel(
    const float* __restrict__ and_k,   // (R,C,NUM_IN,3) flat
    const float* __restrict__ or_k,    // (R,C) flat
    const float* __restrict__ temp,    // (1,)
    float* __restrict__ ak_out,        // d_out + OFF_AK
    float* __restrict__ ok_out,        // d_out + OFF_OK
    float* __restrict__ wt,            // ws: [rc][i]
    float* __restrict__ vt,            // ws: [rc][i]
    float* __restrict__ okw)           // ws: [rc]
{
    int gid = blockIdx.x * 256 + threadIdx.x;   // 0 .. 15359
    float tinv = 1.0f / temp[0];
    if (gid < RC * NUM_IN) {
        float a0 = and_k[gid * 3 + 0] * tinv;
        float a1 = and_k[gid * 3 + 1] * tinv;
        float a2 = and_k[gid * 3 + 2] * tinv;
        float m  = fmaxf(a0, fmaxf(a1, a2));
        float e0 = __expf(a0 - m), e1 = __expf(a1 - m), e2 = __expf(a2 - m);
        float s  = 1.0f / (e0 + e1 + e2);
        float k0 = e0 * s, k1 = e1 * s, k2 = e2 * s;
        ak_out[gid * 3 + 0] = k0;
        ak_out[gid * 3 + 1] = k1;
        ak_out[gid * 3 + 2] = k2;
        wt[gid] = k0 - k1;        // conj_eval = x*w + v
        vt[gid] = k1 + k2;
    }
    if (gid < RC) {
        float o = 1.0f / (1.0f + __expf(-or_k[gid] * tinv));
        ok_out[gid] = o;
        okw[gid]    = o;
    }
}

// ---------------- Kernel 2: main conjunct/disjunct computation
// One block per BPB (b,perm) pairs. Lanes 0..95 own one rc each; table read
// as float4 along i (L2-resident); x broadcast from LDS. NO fences/atomics:
// a per-block device-scope fence cost ~60us across the grid in R3.
__global__ __launch_bounds__(128) void main_kernel(
    const float* __restrict__ nullary,  // (B,32)
    const float* __restrict__ unary,    // (B,16,32)
    const float* __restrict__ binary,   // (B,16,15,32)
    const float* __restrict__ wt,       // ws: [rc][i]
    const float* __restrict__ vt,       // ws: [rc][i]
    const float* __restrict__ okw,      // ws: [rc]
    float* __restrict__ binary_out,     // d_out + OFF_BINARY, [3840]
    float* __restrict__ rules01)        // ws: r0[3840], r1[3840]
{
    int bp0 = blockIdx.x * BPB;
    __shared__ float xs[BPB * NUM_IN];

    int t = threadIdx.x;
    // Gather phase: BPB*160 floats, 128 threads, 32-float coalesced runs
    for (int idx = t; idx < BPB * NUM_IN; idx += 128) {
        int bpl = idx / NUM_IN;
        int i   = idx - bpl * NUM_IN;
        int bp  = bp0 + bpl;
        int bt  = bp / NPERM;
        int p   = bp - bt * NPERM;
        int a   = p / 15;
        int rem = p - a * 15;
        int b   = rem + (rem >= a);
        int bprime = rem;                 // b - (b > a)
        int aprime = a - (a > b);
        int seg = i >> 5, j = i & 31;
        float v;
        if      (seg == 0) v = nullary[bt * 32 + j];
        else if (seg == 1) v = unary[(bt * 16 + a) * 32 + j];
        else if (seg == 2) v = unary[(bt * 16 + b) * 32 + j];
        else if (seg == 3) v = binary[((bt * 16 + a) * 15 + bprime) * 32 + j];
        else               v = binary[((bt * 16 + b) * 15 + aprime) * 32 + j];
        xs[idx] = v;
    }
    __syncthreads();

    if (t < RC) {
        const float4* w4 = (const float4*)wt + t * NI4;
        const float4* v4 = (const float4*)vt + t * NI4;
        const float4* x4 = (const float4*)xs;           // [BPB][NI4]
        float cA[BPB], cB[BPB];
        #pragma unroll
        for (int l = 0; l < BPB; ++l) { cA[l] = 1.0f; cB[l] = 1.0f; }

        #pragma unroll 2
        for (int s = 0; s < NI4; ++s) {
            float4 w = w4[s];
            float4 v = v4[s];
            #pragma unroll
            for (int l = 0; l < BPB; ++l) {
                float4 x = x4[l * NI4 + s];             // LDS broadcast b128
                cA[l] *= fmaf(x.x, w.x, v.x);
                cB[l] *= fmaf(x.y, w.y, v.y);
                cA[l] *= fmaf(x.z, w.z, v.z);
                cB[l] *= fmaf(x.w, w.w, v.w);
            }
        }

        float o = okw[t];
        int r = t >> 5;
        #pragma unroll
        for (int l = 0; l < BPB; ++l) {
            float d = 1.0f - (cA[l] * cB[l]) * o;
            // product across the 32 c-lanes of this r-group
            #pragma unroll
            for (int off = 1; off < 32; off <<= 1)
                d *= __shfl_xor(d, off, 32);
            if ((t & 31) == 0) {
                float dis = 1.0f - d;
                int bp = bp0 + l;
                if (r == 2) binary_out[bp] = dis;
                else        rules01[r * (B_ * NPERM) + bp] = dis;
            }
        }
    }
}

// ---------------- Kernel 3: probsum reductions for nullary (240->1) and unary (15->1)
__global__ __launch_bounds__(256) void finish_kernel(
    const float* __restrict__ rules01,   // ws
    float* __restrict__ nullary_out,     // d_out + OFF_NULLARY, [16]
    float* __restrict__ unary_out)       // d_out + OFF_UNARY, [256]
{
    int bt = blockIdx.x;    // 0..15
    int t  = threadIdx.x;
    const float* r0 = rules01;
    const float* r1 = rules01 + B_ * NPERM;

    // unary: o1 = t/16, lane-in-group covers the 15 o2 slots
    {
        int o1 = t >> 4, l = t & 15;
        float v = (l < 15) ? (1.0f - r1[bt * NPERM + o1 * 15 + l]) : 1.0f;
        #pragma unroll
        for (int off = 1; off < 16; off <<= 1)
            v *= __shfl_xor(v, off, 16);
        if (l == 0) unary_out[bt * 16 + o1] = 1.0f - v;
    }

    // nullary: product over all 240 perms
    {
        float v = (t < NPERM) ? (1.0f - r0[bt * NPERM + t]) : 1.0f;
        #pragma unroll
        for (int off = 1; off < 64; off <<= 1)
            v *= __shfl_xor(v, off, 64);
        __shared__ float wprod[4];
        if ((t & 63) == 0) wprod[t >> 6] = v;
        __syncthreads();
        if (t == 0)
            nullary_out[bt] = 1.0f - wprod[0] * wprod[1] * wprod[2] * wprod[3];
    }
}

extern "C" void kernel_launch(void* const* d_in, const int* in_sizes, int n_in,
                              void* d_out, int out_size, void* d_ws, size_t ws_size,
                              hipStream_t stream) {
    const float* nullary = (const float*)d_in[0];   // (16,32)
    const float* unary   = (const float*)d_in[1];   // (16,16,32)
    const float* binary  = (const float*)d_in[2];   // (16,16,15,32)
    const float* and_k   = (const float*)d_in[3];   // (3,32,160,3)
    const float* or_k    = (const float*)d_in[4];   // (3,32)
    const float* temp    = (const float*)d_in[5];   // (1,)

    float* out = (float*)d_out;
    float* ws  = (float*)d_ws;

    float* wt      = ws + WS_WT;
    float* vt      = ws + WS_VT;
    float* okw     = ws + WS_OK;
    float* rules01 = ws + WS_R01;

    prep_kernel<<<60, 256, 0, stream>>>(and_k, or_k, temp,
                                        out + OFF_AK, out + OFF_OK,
                                        wt, vt, okw);
    main_kernel<<<MAIN_GRID, 128, 0, stream>>>(nullary, unary, binary,
                                               wt, vt, okw,
                                               out + OFF_BINARY, rules01);
    finish_kernel<<<B_, 256, 0, stream>>>(rules01,
                                          out + OFF_NULLARY, out + OFF_UNARY);
}